// Round 2
// baseline (537.660 us; speedup 1.0000x reference)
//
#include <hip/hip_runtime.h>
#include <stdint.h>

// y[t][o] = sum_i x[t][i] * ((w_pos[o][i]>0) - (w_neg[o][i]>0))
// One bf16 GEMM vs ternary weights (ternary is exact in bf16).
// M=8192, N=4096, K=4096. fp32 out.
// ws: [0,64MiB) x_bf16 ; [64MiB,96MiB) tern_bf16.
//
// GEMM: 256x256 tile, BK=64, 8 waves (2Mx4N), 128 KiB LDS double buffer.
// NEW this round: register double-banked 8-phase pipeline — each phase
// issues next phase's ds_reads BEFORE its MFMA cluster (LDS service
// overlaps MFMA exec), single s_barrier per phase, vmcnt(8) at odd
// phases. Previous structure serialized LDS burst (565cy) with MFMA
// (620cy) -> 47.6% MfmaUtil; this overlaps them.

#define TOKENS 8192
#define DIN    4096
#define DOUT   4096

typedef __bf16  bf16x8  __attribute__((ext_vector_type(8)));
typedef float   floatx4 __attribute__((ext_vector_type(4)));

__device__ __forceinline__ void async_copy16(const void* g, void* l) {
  __builtin_amdgcn_global_load_lds(
      (const __attribute__((address_space(1))) void*)g,
      (__attribute__((address_space(3))) void*)l, 16, 0, 0);
}

__device__ __forceinline__ unsigned short f2bf_rne(float f) {
  union { float f; uint32_t u; } v; v.f = f;
  uint32_t u = v.u;
  u += 0x7fffu + ((u >> 16) & 1u);
  return (unsigned short)(u >> 16);
}

__device__ __forceinline__ unsigned short tern_bits(float p, float n) {
  bool bp = p > 0.0f, bn = n > 0.0f;
  return (unsigned short)(bp == bn ? 0u : (bp ? 0x3f80u : 0xbf80u));
}

// Fused prep: blocks [0,8192) convert x fp32->bf16; blocks [8192,12288)
// ternarize w. Both memory-bound, one launch.
__global__ __launch_bounds__(256) void prep_kernel(
    const float4* __restrict__ x, ushort4* __restrict__ xb,
    const float4* __restrict__ wp, const float4* __restrict__ wn,
    ushort4* __restrict__ t) {
  const uint32_t bid = blockIdx.x;
  if (bid < 8192u) {
    const uint32_t stride = 8192u * 256u;
    uint32_t i = bid * 256u + threadIdx.x;
#pragma unroll
    for (int it = 0; it < 4; ++it, i += stride) {
      float4 v = x[i];
      ushort4 o;
      o.x = f2bf_rne(v.x); o.y = f2bf_rne(v.y);
      o.z = f2bf_rne(v.z); o.w = f2bf_rne(v.w);
      xb[i] = o;
    }
  } else {
    const uint32_t stride = 4096u * 256u;
    uint32_t i = (bid - 8192u) * 256u + threadIdx.x;
#pragma unroll
    for (int it = 0; it < 4; ++it, i += stride) {
      float4 p = wp[i];
      float4 n = wn[i];
      ushort4 o;
      o.x = tern_bits(p.x, n.x);
      o.y = tern_bits(p.y, n.y);
      o.z = tern_bits(p.z, n.z);
      o.w = tern_bits(p.w, n.w);
      t[i] = o;
    }
  }
}

// ---------------------------------------------------------------------------
// GEMM C[M,N] = A[M,K] * B[N,K]^T, bf16 in, fp32 out.
//
// LDS map (per buffer b in {0,1}, base b*65536):
//   A tile: [+0]      khalf0 = [256 rows][64 B], khalf1 at +16384
//   B tile: [+32768]  same layout
// Chunk swizzle: 64-B row = 4 chunks of 16 B; chunk c stored at slot
// c ^ ((row>>1)&3). Applied on pre-swizzled GLOBAL source (staging keeps
// linear lane->LDS) and on LDS read address (fragments). Conflict-free.
//
// Pipeline (steady state, iter i: buf0=tile 2i, buf1=tile 2i+1):
//   Phase P: [ lgkmcnt(0)            -- bank issued at P-1 now ready
//              issue ds_reads bank(P) for MFMA(P+1)
//              16 MFMA on bank(P-1)  -- overlaps LDS service of bank(P)
//              stage S(P)            -- 2 global_load_lds
//              vmcnt(8) if P odd     -- RAW guard, >=4-phase tolerance
//              s_barrier ]
// Read-issue map: Ph1:A0k0h1 Ph2:A0k1h0+B0k1 Ph3:A0k1h1 Ph4:A1k0h0+B1k0
//   Ph5:A1k0h1 Ph6:A1k1h0+B1k1 Ph7:A1k1h1 Ph8:next A0k0h0+B0k0
// Stage map:      Ph1:b1.Ak1(T2i+1) Ph2:b0.Bk0 Ph3:b0.Ak0 Ph4:b0.Bk1
//   Ph5:b0.Ak1 (all T2i+2) Ph6:b1.Bk0 Ph7:b1.Ak0 Ph8:b1.Bk1 (T2i+3)
// Verified: stage S(P) disjoint from read regions of P and P-1; WAR via
// lgkm0 + barrier (stage >= last-read-issue + 2 phases, all regions);
// RAW: VM8@odd retires exactly the 2 stages the next read-issue needs.
// ---------------------------------------------------------------------------

#define LDS_BUF   65536u
#define LDS_B_OFF 32768u
#define LDS_KC    16384u

__global__ __launch_bounds__(512, 2) void gemm_bt(
    const unsigned short* __restrict__ A,   // [TOKENS][DIN] bf16
    const unsigned short* __restrict__ B,   // [DOUT][DIN]   bf16 ternary
    float* __restrict__ C)                  // [TOKENS][DOUT] fp32
{
  __shared__ __align__(16) char lds[131072];

  const int tid   = threadIdx.x;
  const int lane  = tid & 63;
  const int wid   = tid >> 6;
  const int waveM = wid >> 2;   // 0..1
  const int waveN = wid & 3;    // 0..3

  // Bijective XCD swizzle: 512 blocks = 8 XCDs x 64 contiguous tiles.
  const uint32_t flat = blockIdx.x;
  const uint32_t swz  = ((flat & 7u) << 6) | (flat >> 3);
  const uint32_t bm = (swz >> 4) * 256u;    // 0..31 -> M
  const uint32_t bn = (swz & 15u) * 256u;   // 0..15 -> N

  // Staging: thread covers 16 B at region offset wid*2048 + lane*16.
  const uint32_t srow  = (uint32_t)(tid >> 6) * 32u + (uint32_t)((tid & 63) >> 2);
  const uint32_t slot  = (uint32_t)(tid & 3);
  const uint32_t chnk  = slot ^ ((srow >> 1) & 3u);   // pre-swizzled global chunk
  const uint32_t stA   = (bm + srow) * (DIN * 2u) + chnk * 16u;
  const uint32_t stB   = (bn + srow) * (DIN * 2u) + chnk * 16u;
  const uint32_t ldsSt = (uint32_t)(tid >> 6) * 2048u + (uint32_t)(tid & 63) * 16u;
  const char* Ab = (const char*)A;
  const char* Bb = (const char*)B;

  // Fragment read constants.
  const int mrow = lane & 15;
  const int q    = lane >> 4;
  const int xs   = (q ^ ((mrow >> 1) & 3)) * 16;
  const uint32_t aFragBase = (uint32_t)waveM * 8192u + (uint32_t)mrow * 64u + (uint32_t)xs;
  const uint32_t bFragBase = LDS_B_OFF + (uint32_t)waveN * 4096u
                           + (uint32_t)mrow * 64u + (uint32_t)xs;

  floatx4 acc[8][4];
#pragma unroll
  for (int m = 0; m < 8; ++m)
#pragma unroll
    for (int n = 0; n < 4; ++n)
      acc[m][n] = (floatx4)0.0f;

  bf16x8 a0[4], a1[4], b0[4], b1[4];   // double-banked fragments

#define STAGE_A(BUF, KH, KB) do {                                          \
    uint32_t g_ = stA + (KB) + (KH) * 64u;                                 \
    uint32_t l_ = (BUF) * LDS_BUF + (KH) * LDS_KC + ldsSt;                 \
    async_copy16(Ab + g_,           lds + l_);                             \
    async_copy16(Ab + g_ + 131072u, lds + l_ + 1024u);                     \
  } while (0)

#define STAGE_B(BUF, KH, KB) do {                                          \
    uint32_t g_ = stB + (KB) + (KH) * 64u;                                 \
    uint32_t l_ = (BUF) * LDS_BUF + LDS_B_OFF + (KH) * LDS_KC + ldsSt;     \
    async_copy16(Bb + g_,           lds + l_);                             \
    async_copy16(Bb + g_ + 131072u, lds + l_ + 1024u);                     \
  } while (0)

#define IA(DST, BUF, KC, MH) do {                                          \
    _Pragma("unroll")                                                      \
    for (int m_ = 0; m_ < 4; ++m_)                                         \
      DST[m_] = *(const bf16x8*)(lds + (BUF) * LDS_BUF + (KC) * LDS_KC     \
                                 + (uint32_t)(m_ + (MH) * 4) * 1024u       \
                                 + aFragBase);                             \
  } while (0)

#define IB(DST, BUF, KC) do {                                              \
    _Pragma("unroll")                                                      \
    for (int n_ = 0; n_ < 4; ++n_)                                         \
      DST[n_] = *(const bf16x8*)(lds + (BUF) * LDS_BUF + (KC) * LDS_KC     \
                                 + (uint32_t)n_ * 1024u + bFragBase);      \
  } while (0)

#define VM8 asm volatile("s_waitcnt vmcnt(8)" ::: "memory")
#define NOPW ((void)0)

#define PHASE(MH, AV, BV, ISSUE_STMT, STAGE_STMT, VMW) do {                \
    asm volatile("s_waitcnt lgkmcnt(0)" ::: "memory");                     \
    __builtin_amdgcn_sched_barrier(0);                                     \
    ISSUE_STMT;                                                            \
    __builtin_amdgcn_sched_barrier(0);                                     \
    __builtin_amdgcn_s_setprio(1);                                         \
    _Pragma("unroll")                                                      \
    for (int m_ = 0; m_ < 4; ++m_)                                         \
      _Pragma("unroll")                                                    \
      for (int n_ = 0; n_ < 4; ++n_)                                       \
        acc[(MH) * 4 + m_][n_] = __builtin_amdgcn_mfma_f32_16x16x32_bf16(  \
            AV[m_], BV[n_], acc[(MH) * 4 + m_][n_], 0, 0, 0);              \
    __builtin_amdgcn_s_setprio(0);                                         \
    STAGE_STMT;                                                            \
    VMW;                                                                   \
    __builtin_amdgcn_s_barrier();                                          \
  } while (0)

  // Prologue. Stage order fixed: the 5 loads left in flight at loop entry
  // must be (oldest first) b0.Bk1, b0.Ak1, b1.Bk0, b1.Ak0, b1.Bk1.
  STAGE_B(0, 0, 0u);   STAGE_A(0, 0, 0u);
  STAGE_B(0, 1, 0u);   STAGE_A(0, 1, 0u);
  STAGE_B(1, 0, 128u); STAGE_A(1, 0, 128u);
  STAGE_B(1, 1, 128u);
  asm volatile("s_waitcnt vmcnt(10)" ::: "memory");   // buf0.kc0 landed
  __builtin_amdgcn_s_barrier();
  IB(b0, 0, 0); IA(a0, 0, 0, 0);   // prime bank for Ph1's MFMA

#pragma unroll 1
  for (int i = 0; i < 32; ++i) {
    const uint32_t kb1 = (uint32_t)(2 * i + 1) * 128u;
    const uint32_t kb2 = (uint32_t)((2 * i + 2) & 63) * 128u;  // wraps: valid mem, never read
    const uint32_t kb3 = (uint32_t)((2 * i + 3) & 63) * 128u;

    PHASE(0, a0, b0, IA(a1, 0, 0, 1),                  STAGE_A(1, 1, kb1), VM8);  // Ph1
    PHASE(1, a1, b0, { IB(b1, 0, 1); IA(a0, 0, 1, 0); }, STAGE_B(0, 0, kb2), NOPW); // Ph2
    PHASE(0, a0, b1, IA(a1, 0, 1, 1),                  STAGE_A(0, 0, kb2), VM8);  // Ph3
    PHASE(1, a1, b1, { IB(b0, 1, 0); IA(a0, 1, 0, 0); }, STAGE_B(0, 1, kb2), NOPW); // Ph4
    PHASE(0, a0, b0, IA(a1, 1, 0, 1),                  STAGE_A(0, 1, kb2), VM8);  // Ph5
    PHASE(1, a1, b0, { IB(b1, 1, 1); IA(a0, 1, 1, 0); }, STAGE_B(1, 0, kb3), NOPW); // Ph6
    PHASE(0, a0, b1, IA(a1, 1, 1, 1),                  STAGE_A(1, 0, kb3), VM8);  // Ph7
    PHASE(1, a1, b1, { IB(b0, 0, 0); IA(a0, 0, 0, 0); }, STAGE_B(1, 1, kb3), NOPW); // Ph8
  }

  // C/D layout: col = lane&15, row = (lane>>4)*4 + reg.
  const int col0 = (int)bn + waveN * 64 + (lane & 15);
  const int row0 = (int)bm + waveM * 128 + (lane >> 4) * 4;
  float* Cp = C + (size_t)row0 * DOUT + col0;
#pragma unroll
  for (int m = 0; m < 8; ++m)
#pragma unroll
    for (int n = 0; n < 4; ++n)
#pragma unroll
      for (int r = 0; r < 4; ++r)
        Cp[(size_t)(m * 16 + r) * DOUT + n * 16] = acc[m][n][r];

#undef STAGE_A
#undef STAGE_B
#undef IA
#undef IB
#undef VM8
#undef NOPW
#undef PHASE
}

extern "C" void kernel_launch(void* const* d_in, const int* in_sizes, int n_in,
                              void* d_out, int out_size, void* d_ws, size_t ws_size,
                              hipStream_t stream) {
  const float* x  = (const float*)d_in[0];   // [8192, 4096] fp32
  const float* wp = (const float*)d_in[1];   // [4096, 4096] fp32
  const float* wn = (const float*)d_in[2];   // [4096, 4096] fp32
  float* out = (float*)d_out;                // [8192, 4096] fp32

  unsigned short* xb   = (unsigned short*)d_ws;
  unsigned short* tern = xb + (size_t)TOKENS * DIN;

  // Fused prep: 8192 cvt blocks + 4096 tern blocks.
  prep_kernel<<<12288, 256, 0, stream>>>(
      (const float4*)x, (ushort4*)xb,
      (const float4*)wp, (const float4*)wn, (ushort4*)tern);

  // 512 blocks (1D, XCD-swizzled in-kernel) x 512 threads.
  gemm_bt<<<TOKENS / 256 * (DOUT / 256), 512, 0, stream>>>(xb, tern, out);
}

// Round 3
// 537.057 us; speedup vs baseline: 1.0011x; 1.0011x over previous
//
#include <hip/hip_runtime.h>
#include <stdint.h>

// y[t][o] = sum_i x[t][i] * ((w_pos[o][i]>0) - (w_neg[o][i]>0))
// One bf16 GEMM vs ternary weights (ternary is exact in bf16).
// M=8192, N=4096, K=4096. fp32 out.
// ws: [0,64MiB) x_bf16 ; [64MiB,96MiB) tern_bf16.
//
// GEMM: 256x256 tile, BK=64, 8 waves (2Mx4N), 128 KiB LDS double buffer.
// NEW this round: fragment loads are inline-asm ds_read_b128 (opaque to
// the compiler's waitcnt pass) so the compiler cannot insert a
// conservative lgkmcnt(0) before the MFMA cluster that drains the
// next-phase reads. Manual lgkmcnt(0) + vmcnt(8) at phase top only.
// Issue balanced to 6 reads/phase (4 A + 2 B-half).

#define TOKENS 8192
#define DIN    4096
#define DOUT   4096

typedef __bf16  bf16x8  __attribute__((ext_vector_type(8)));
typedef float   floatx4 __attribute__((ext_vector_type(4)));

__device__ __forceinline__ void async_copy16(const void* g, void* l) {
  __builtin_amdgcn_global_load_lds(
      (const __attribute__((address_space(1))) void*)g,
      (__attribute__((address_space(3))) void*)l, 16, 0, 0);
}

__device__ __forceinline__ unsigned short f2bf_rne(float f) {
  union { float f; uint32_t u; } v; v.f = f;
  uint32_t u = v.u;
  u += 0x7fffu + ((u >> 16) & 1u);
  return (unsigned short)(u >> 16);
}

__device__ __forceinline__ unsigned short tern_bits(float p, float n) {
  bool bp = p > 0.0f, bn = n > 0.0f;
  return (unsigned short)(bp == bn ? 0u : (bp ? 0x3f80u : 0xbf80u));
}

// Fused prep: blocks [0,8192) convert x fp32->bf16; blocks [8192,12288)
// ternarize w. Both memory-bound, one launch.
__global__ __launch_bounds__(256) void prep_kernel(
    const float4* __restrict__ x, ushort4* __restrict__ xb,
    const float4* __restrict__ wp, const float4* __restrict__ wn,
    ushort4* __restrict__ t) {
  const uint32_t bid = blockIdx.x;
  if (bid < 8192u) {
    const uint32_t stride = 8192u * 256u;
    uint32_t i = bid * 256u + threadIdx.x;
#pragma unroll
    for (int it = 0; it < 4; ++it, i += stride) {
      float4 v = x[i];
      ushort4 o;
      o.x = f2bf_rne(v.x); o.y = f2bf_rne(v.y);
      o.z = f2bf_rne(v.z); o.w = f2bf_rne(v.w);
      xb[i] = o;
    }
  } else {
    const uint32_t stride = 4096u * 256u;
    uint32_t i = (bid - 8192u) * 256u + threadIdx.x;
#pragma unroll
    for (int it = 0; it < 4; ++it, i += stride) {
      float4 p = wp[i];
      float4 n = wn[i];
      ushort4 o;
      o.x = tern_bits(p.x, n.x);
      o.y = tern_bits(p.y, n.y);
      o.z = tern_bits(p.z, n.z);
      o.w = tern_bits(p.w, n.w);
      t[i] = o;
    }
  }
}

// ---------------------------------------------------------------------------
// GEMM C[M,N] = A[M,K] * B[N,K]^T, bf16 in, fp32 out.
//
// LDS map (per buffer b in {0,1}, base b*65536):
//   A tile: [+0]      khalf0 = [256 rows][64 B], khalf1 at +16384
//   B tile: [+32768]  same layout
// Chunk swizzle: 64-B row = 4 chunks of 16 B; chunk c stored at slot
// c ^ ((row>>1)&3). Applied on pre-swizzled GLOBAL source (staging keeps
// linear lane->LDS) and on LDS read address (fragments). Conflict-free.
//
// Phase P: [ lgkmcnt(0)  -- prev phase's 6 reads now retired
//            vmcnt(8)    -- RAW horizon: retires stage of phase P-5
//            issue 6 asm ds_read_b128 (4 A + 2 B-half) for P+1/P+2
//            16 MFMA on banks loaded at P-1 (LDS services reads meanwhile)
//            stage (2 global_load_lds)
//            s_barrier ]
// Read map (bank <- region; b-banks split into halves):
//   Ph1: a1<-b0.Ak0h1, b1[01]<-b0.Bk1 | Ph2: a0<-b0.Ak1h0, b1[23]
//   Ph3: a1<-b0.Ak1h1, b0[01]<-b1.Bk0 | Ph4: a0<-b1.Ak0h0, b0[23]
//   Ph5: a1<-b1.Ak0h1, b1[01]<-b1.Bk1 | Ph6: a0<-b1.Ak1h0, b1[23]
//   Ph7: a1<-b1.Ak1h1, b0[01]<-b0.Bk0'| Ph8: a0<-b0.Ak0'h0, b0[23]
// Stage map (unchanged, verified R2): Ph1:b1.Ak1(T2i+1) Ph2:b0.Bk0
//   Ph3:b0.Ak0 Ph4:b0.Bk1 Ph5:b0.Ak1 (T2i+2) Ph6:b1.Bk0 Ph7:b1.Ak0
//   Ph8:b1.Bk1 (T2i+3).
// RAW: every read's source stage is >= 1 phase older than its phase's
// vmcnt(8) horizon (checked all regions + prologue). WAR: each staged
// region's last ds_read retires (lgkm0) >= 1 barrier before the stage.
// ---------------------------------------------------------------------------

#define LDS_BUF   65536u
#define LDS_B_OFF 32768u
#define LDS_KC    16384u

__global__ __launch_bounds__(512, 2) void gemm_bt(
    const unsigned short* __restrict__ A,   // [TOKENS][DIN] bf16
    const unsigned short* __restrict__ B,   // [DOUT][DIN]   bf16 ternary
    float* __restrict__ C)                  // [TOKENS][DOUT] fp32
{
  __shared__ __align__(16) char lds[131072];

  const int tid   = threadIdx.x;
  const int lane  = tid & 63;
  const int wid   = tid >> 6;
  const int waveM = wid >> 2;   // 0..1
  const int waveN = wid & 3;    // 0..3

  // Bijective XCD swizzle: 512 blocks = 8 XCDs x 64 contiguous tiles.
  const uint32_t flat = blockIdx.x;
  const uint32_t swz  = ((flat & 7u) << 6) | (flat >> 3);
  const uint32_t bm = (swz >> 4) * 256u;    // 0..31 -> M
  const uint32_t bn = (swz & 15u) * 256u;   // 0..15 -> N

  // Staging: thread covers 16 B at region offset wid*2048 + lane*16.
  const uint32_t srow  = (uint32_t)(tid >> 6) * 32u + (uint32_t)((tid & 63) >> 2);
  const uint32_t slot  = (uint32_t)(tid & 3);
  const uint32_t chnk  = slot ^ ((srow >> 1) & 3u);   // pre-swizzled global chunk
  const uint32_t stA   = (bm + srow) * (DIN * 2u) + chnk * 16u;
  const uint32_t stB   = (bn + srow) * (DIN * 2u) + chnk * 16u;
  const uint32_t ldsSt = (uint32_t)(tid >> 6) * 2048u + (uint32_t)(tid & 63) * 16u;
  const char* Ab = (const char*)A;
  const char* Bb = (const char*)B;

  // Fragment read constants (swizzled LDS byte addresses).
  const int mrow = lane & 15;
  const int q    = lane >> 4;
  const int xs   = (q ^ ((mrow >> 1) & 3)) * 16;
  const uint32_t ldsBase =
      (uint32_t)(uintptr_t)(__attribute__((address_space(3))) char*)lds;
  const uint32_t aFragBase = (uint32_t)waveM * 8192u + (uint32_t)mrow * 64u + (uint32_t)xs;
  const uint32_t bFragBase = LDS_B_OFF + (uint32_t)waveN * 4096u
                           + (uint32_t)mrow * 64u + (uint32_t)xs;
  const uint32_t aA0 = ldsBase + aFragBase;            // buf0 A base
  const uint32_t aA1 = aA0 + LDS_BUF;                  // buf1 A base
  const uint32_t bA0 = ldsBase + bFragBase;            // buf0 B base
  const uint32_t bA1 = bA0 + LDS_BUF;                  // buf1 B base

  floatx4 acc[8][4];
#pragma unroll
  for (int m = 0; m < 8; ++m)
#pragma unroll
    for (int n = 0; n < 4; ++n)
      acc[m][n] = (floatx4)0.0f;

  // Double-banked fragments (asm outputs; 128-bit each).
  floatx4 a0f[4], a1f[4], b0f[4], b1f[4];

#define DSR(DST, ADDR, IMM)                                                \
  asm volatile("ds_read_b128 %0, %1 offset:%c2"                            \
               : "=v"(DST) : "v"(ADDR), "i"(IMM))

#define IA4(DST, ADDR, KC, MH) do {                                        \
    DSR(DST[0], ADDR, (KC) * 16384 + ((MH) * 4 + 0) * 1024);               \
    DSR(DST[1], ADDR, (KC) * 16384 + ((MH) * 4 + 1) * 1024);               \
    DSR(DST[2], ADDR, (KC) * 16384 + ((MH) * 4 + 2) * 1024);               \
    DSR(DST[3], ADDR, (KC) * 16384 + ((MH) * 4 + 3) * 1024);               \
  } while (0)

#define IB2(DST, N0, ADDR, KC) do {                                        \
    DSR(DST[N0],     ADDR, (KC) * 16384 + ((N0)) * 1024);                  \
    DSR(DST[N0 + 1], ADDR, (KC) * 16384 + ((N0) + 1) * 1024);              \
  } while (0)

#define STAGE_A(BUF, KH, KB) do {                                          \
    uint32_t g_ = stA + (KB) + (KH) * 64u;                                 \
    uint32_t l_ = (BUF) * LDS_BUF + (KH) * LDS_KC + ldsSt;                 \
    async_copy16(Ab + g_,           lds + l_);                             \
    async_copy16(Ab + g_ + 131072u, lds + l_ + 1024u);                     \
  } while (0)

#define STAGE_B(BUF, KH, KB) do {                                          \
    uint32_t g_ = stB + (KB) + (KH) * 64u;                                 \
    uint32_t l_ = (BUF) * LDS_BUF + LDS_B_OFF + (KH) * LDS_KC + ldsSt;     \
    async_copy16(Bb + g_,           lds + l_);                             \
    async_copy16(Bb + g_ + 131072u, lds + l_ + 1024u);                     \
  } while (0)

#define PHASE(MH, AF, BF, ISSUE_STMT, STAGE_STMT) do {                     \
    asm volatile("s_waitcnt lgkmcnt(0)" ::: "memory");                     \
    asm volatile("s_waitcnt vmcnt(8)" ::: "memory");                       \
    __builtin_amdgcn_sched_barrier(0);                                     \
    ISSUE_STMT;                                                            \
    __builtin_amdgcn_sched_barrier(0);                                     \
    __builtin_amdgcn_s_setprio(1);                                         \
    _Pragma("unroll")                                                      \
    for (int m_ = 0; m_ < 4; ++m_)                                         \
      _Pragma("unroll")                                                    \
      for (int n_ = 0; n_ < 4; ++n_)                                       \
        acc[(MH) * 4 + m_][n_] = __builtin_amdgcn_mfma_f32_16x16x32_bf16(  \
            __builtin_bit_cast(bf16x8, AF[m_]),                            \
            __builtin_bit_cast(bf16x8, BF[n_]),                            \
            acc[(MH) * 4 + m_][n_], 0, 0, 0);                              \
    __builtin_amdgcn_s_setprio(0);                                         \
    STAGE_STMT;                                                            \
    __builtin_amdgcn_s_barrier();                                          \
  } while (0)

  // Prologue: stage 7 regions in the steady-state stage-map order
  // (pseudo-phases Ph2'..Ph8'), drain to the first 3, prime banks.
  STAGE_B(0, 0, 0u);    // Ph2': b0.Bk0
  STAGE_A(0, 0, 0u);    // Ph3': b0.Ak0
  STAGE_B(0, 1, 0u);    // Ph4': b0.Bk1
  STAGE_A(0, 1, 0u);    // Ph5': b0.Ak1
  STAGE_B(1, 0, 128u);  // Ph6': b1.Bk0
  STAGE_A(1, 0, 128u);  // Ph7': b1.Ak0
  STAGE_B(1, 1, 128u);  // Ph8': b1.Bk1
  asm volatile("s_waitcnt vmcnt(8)" ::: "memory");   // Bk0,Ak0,Bk1 landed
  __builtin_amdgcn_s_barrier();
  // Prime: b0f <- buf0.B.kc0, a0f <- buf0.A.kc0 mh0 (for Ph1's MFMA).
  IB2(b0f, 0, bA0, 0); IB2(b0f, 2, bA0, 0 + 0);
  DSR(b0f[0], bA0, 0); DSR(b0f[1], bA0, 1024);
  DSR(b0f[2], bA0, 2048); DSR(b0f[3], bA0, 3072);
  IA4(a0f, aA0, 0, 0);

#pragma unroll 1
  for (int i = 0; i < 32; ++i) {
    const uint32_t kb1 = (uint32_t)(2 * i + 1) * 128u;
    const uint32_t kb2 = (uint32_t)((2 * i + 2) & 63) * 128u;  // wraps: valid mem, never read
    const uint32_t kb3 = (uint32_t)((2 * i + 3) & 63) * 128u;

    PHASE(0, a0f, b0f, { IA4(a1f, aA0, 0, 1); IB2(b1f, 0, bA0, 1); },
          STAGE_A(1, 1, kb1));                                            // Ph1
    PHASE(1, a1f, b0f, { IA4(a0f, aA0, 1, 0); IB2(b1f, 2, bA0, 1); },
          STAGE_B(0, 0, kb2));                                            // Ph2
    PHASE(0, a0f, b1f, { IA4(a1f, aA0, 1, 1); IB2(b0f, 0, bA1, 0); },
          STAGE_A(0, 0, kb2));                                            // Ph3
    PHASE(1, a1f, b1f, { IA4(a0f, aA1, 0, 0); IB2(b0f, 2, bA1, 0); },
          STAGE_B(0, 1, kb2));                                            // Ph4
    PHASE(0, a0f, b0f, { IA4(a1f, aA1, 0, 1); IB2(b1f, 0, bA1, 1); },
          STAGE_A(0, 1, kb2));                                            // Ph5
    PHASE(1, a1f, b0f, { IA4(a0f, aA1, 1, 0); IB2(b1f, 2, bA1, 1); },
          STAGE_B(1, 0, kb3));                                            // Ph6
    PHASE(0, a0f, b1f, { IA4(a1f, aA1, 1, 1); IB2(b0f, 0, bA0, 0); },
          STAGE_A(1, 0, kb3));                                            // Ph7
    PHASE(1, a1f, b1f, { IA4(a0f, aA0, 0, 0); IB2(b0f, 2, bA0, 0); },
          STAGE_B(1, 1, kb3));                                            // Ph8
  }

  // C/D layout: col = lane&15, row = (lane>>4)*4 + reg.
  const int col0 = (int)bn + waveN * 64 + (lane & 15);
  const int row0 = (int)bm + waveM * 128 + (lane >> 4) * 4;
  float* Cp = C + (size_t)row0 * DOUT + col0;
#pragma unroll
  for (int m = 0; m < 8; ++m)
#pragma unroll
    for (int n = 0; n < 4; ++n)
#pragma unroll
      for (int r = 0; r < 4; ++r)
        Cp[(size_t)(m * 16 + r) * DOUT + n * 16] = acc[m][n][r];

#undef DSR
#undef IA4
#undef IB2
#undef STAGE_A
#undef STAGE_B
#undef PHASE
}

extern "C" void kernel_launch(void* const* d_in, const int* in_sizes, int n_in,
                              void* d_out, int out_size, void* d_ws, size_t ws_size,
                              hipStream_t stream) {
  const float* x  = (const float*)d_in[0];   // [8192, 4096] fp32
  const float* wp = (const float*)d_in[1];   // [4096, 4096] fp32
  const float* wn = (const float*)d_in[2];   // [4096, 4096] fp32
  float* out = (float*)d_out;                // [8192, 4096] fp32

  unsigned short* xb   = (unsigned short*)d_ws;
  unsigned short* tern = xb + (size_t)TOKENS * DIN;

  // Fused prep: 8192 cvt blocks + 4096 tern blocks.
  prep_kernel<<<12288, 256, 0, stream>>>(
      (const float4*)x, (ushort4*)xb,
      (const float4*)wp, (const float4*)wn, (ushort4*)tern);

  // 512 blocks (1D, XCD-swizzled in-kernel) x 512 threads.
  gemm_bt<<<TOKENS / 256 * (DOUT / 256), 512, 0, stream>>>(xb, tern, out);
}